// Round 9
// baseline (105.137 us; speedup 1.0000x reference)
//
#include <hip/hip_runtime.h>

#define GAMMA 0.99f
constexpr int T_DIM = 128;
constexpr int B_DIM = 512;
constexpr int Q_DIM = 50;
constexpr int NROW  = (T_DIM - 1) * B_DIM;   // 65024 loss rows (t<127)
constexpr int HSLOT = 28;                    // half2 words per ret row (112B, 16B-aligned)
constexpr int PACC  = 52;                    // f32 partial-row stride
constexpr int R_BLK = 20;                    // ret rows per block
constexpr int KEEP  = -1;
constexpr int GRID_LOSS = (NROW + R_BLK - 1) / R_BLK;   // 3252

typedef _Float16 h2 __attribute__((ext_vector_type(2)));

// ---------------------------------------------------------------------------
// K1: parallel segmented suffix scan of affine maps, one block per b.
// ret[t,b,q] = alpha*tv[anchor,b,q] + beta.  Hillis-Steele over 128 t's:
// 7 LDS rounds, no serial memory chains.  Coeff layout [b][128].
// Thread 127 also writes the required zero at out[127*B+b] (no memset node).
// ---------------------------------------------------------------------------
__global__ void __launch_bounds__(128) coeff_kernel(
    const float* __restrict__ reward,
    const int*   __restrict__ step_type,
    const float* __restrict__ discount,
    float* __restrict__ alpha,
    float* __restrict__ beta,
    int*   __restrict__ anchor,
    float* __restrict__ out) {
  __shared__ float sp[128], sqa[128], sqb[128];
  __shared__ int   snv[128];
  const int t = threadIdx.x;
  const int b = blockIdx.x;

  float p, qa, qb; int nv;
  if (t < T_DIM - 1) {
    const bool  last = (step_type[t * B_DIM + b] == 2);
    const float d    = GAMMA * discount[(t + 1) * B_DIM + b];
    const float r    = reward[(t + 1) * B_DIM + b];
    p  = last ? 0.0f : d;
    qa = last ? 1.0f : 0.0f;
    qb = last ? 0.0f : r;
    nv = last ? t    : KEEP;
  } else {                       // t = 127: identity element
    p = 1.0f; qa = 0.0f; qb = 0.0f; nv = KEEP;
    out[(T_DIM - 1) * B_DIM + b] = 0.0f;     // zero row of the output
  }
  sp[t] = p; sqa[t] = qa; sqb[t] = qb; snv[t] = nv;
  __syncthreads();

#pragma unroll
  for (int off = 1; off < 128; off <<= 1) {
    const bool act = (t + off) < 128;
    float p2 = 1.0f, qa2 = 0.0f, qb2 = 0.0f; int nv2 = KEEP;
    if (act) { p2 = sp[t+off]; qa2 = sqa[t+off]; qb2 = sqb[t+off]; nv2 = snv[t+off]; }
    __syncthreads();
    if (act) {
      qa = fmaf(p, qa2, qa);     // self is the OUTER map (applied last)
      qb = fmaf(p, qb2, qb);
      p  = p * p2;
      nv = (nv == KEEP) ? nv2 : nv;
      sp[t] = p; sqa[t] = qa; sqb[t] = qb; snv[t] = nv;
    }
    __syncthreads();
  }

  if (t < T_DIM - 1) {
    const int row = (b << 7) + t;            // [b][128] layout
    alpha[row]  = p + qa;                    // applied to a-init = 1
    beta[row]   = qb;                        // applied to be-init = 0
    anchor[row] = (nv == KEEP) ? (T_DIM - 1) : nv;
  }
}

// ---------------------------------------------------------------------------
// K2: quantile huber loss, packed-f16 pair math (2 pairs / VOP3P instr),
// via clang vector builtins (ROCm header lacks __hmin2/__hmax2).
// R6 mapping: thread = (r_off=tid/50, j=tid%50), 250 active; 5 rows/pass,
// 4 passes over R_BLK=20 rows staged in LDS as half2.
// Per half2 word u=(ret_i, ret_{i+1}) vs v2=(v,v):  [~7 ops / 2 pairs]
//   d=u-v2; c=min(max(d,-1),1); e=fma(-.5,c,d)
//   s1+=e*c (huber); s2+=e*|c| (sgn*huber)
//   sum w*h = 0.5*S1 + (tau-0.5)*S2;  packed accs flushed to f32 2x/row.
// ---------------------------------------------------------------------------
__global__ void __launch_bounds__(256) loss_kernel(
    const float* __restrict__ value,
    const float* __restrict__ tv,
    const float* __restrict__ alpha,
    const float* __restrict__ beta,
    const int*   __restrict__ anchor,
    float*       __restrict__ out) {
  __shared__ __align__(16) h2 sret[R_BLK * HSLOT];
  __shared__ float pacc[R_BLK * PACC];

  const int tid = threadIdx.x;
  const int r0  = blockIdx.x * R_BLK;

  // ---- stage ret rows r0..r0+19 into LDS as f16 (500 half2 words) ----
  for (int e = tid; e < R_BLK * 25; e += 256) {
    const int lr  = e / 25;
    const int w   = e - lr * 25;
    const int row = r0 + lr;
    float x0 = 0.0f, x1 = 0.0f;
    if (row < NROW) {
      const int b  = row & (B_DIM - 1);
      const int t  = row >> 9;
      const int ci = (b << 7) + t;          // coeff [b][128] layout
      const int n  = anchor[ci];
      const float a  = alpha[ci];
      const float be = beta[ci];
      // tv rows are 200B-strided -> every float2 is 8B-aligned.
      const float2 t2 =
          *reinterpret_cast<const float2*>(tv + (n * B_DIM + b) * Q_DIM + 2 * w);
      x0 = fmaf(a, t2.x, be);
      x1 = fmaf(a, t2.y, be);
    }
    h2 hw; hw.x = (_Float16)x0; hw.y = (_Float16)x1;
    sret[lr * HSLOT + w] = hw;
  }
  __syncthreads();

  const bool act   = tid < 250;
  const int  r_off = tid / 50;              // 0..4
  const int  j     = tid - r_off * 50;
  const float tm05 = ((float)j + 0.5f) * (1.0f / Q_DIM) - 0.5f;

  if (act) {
    // hoisted, fully-coalesced value loads.  Tail-block overrun stays
    // inside value's t=127 rows (results discarded by the guarded store).
    float vv[4];
#pragma unroll
    for (int rb = 0; rb < 4; ++rb)
      vv[rb] = value[(r0 + rb * 5) * Q_DIM + tid];

    h2 n1; n1.x = (_Float16)(-1.0f); n1.y = (_Float16)(-1.0f);
    h2 p1; p1.x = (_Float16)( 1.0f); p1.y = (_Float16)( 1.0f);
    h2 nh; nh.x = (_Float16)(-0.5f); nh.y = (_Float16)(-0.5f);

#pragma unroll
    for (int rb = 0; rb < 4; ++rb) {
      const int lr = rb * 5 + r_off;        // 0..19
      const h2* rp = &sret[lr * HSLOT];
      h2 v2; v2.x = (_Float16)vv[rb]; v2.y = v2.x;

      float S1 = 0.0f, S2 = 0.0f;
      h2 s1; s1.x = (_Float16)0.0f; s1.y = s1.x;
      h2 s2 = s1;

      auto word = [&](h2 u) {
        const h2 d = u - v2;
        const h2 c = __builtin_elementwise_min(
                         __builtin_elementwise_max(d, n1), p1);
        const h2 e = __builtin_elementwise_fma(nh, c, d);
        s1 = __builtin_elementwise_fma(e, c, s1);
        s2 = __builtin_elementwise_fma(e, __builtin_elementwise_abs(c), s2);
      };
      auto flush = [&]() {
        S1 += (float)s1.x + (float)s1.y;
        S2 += (float)s2.x + (float)s2.y;
        s1.x = (_Float16)0.0f; s1.y = s1.x;
        s2 = s1;
      };
      auto as_h2 = [](float f) {
        union { float f; h2 h; } u; u.f = f; return u.h;
      };

      // words 0..11 (3x b128), flush; words 12..23 (3x b128) + word 24, flush
#pragma unroll
      for (int w0 = 0; w0 < 12; w0 += 4) {
        const float4 q = *reinterpret_cast<const float4*>(rp + w0);
        word(as_h2(q.x)); word(as_h2(q.y)); word(as_h2(q.z)); word(as_h2(q.w));
      }
      flush();
#pragma unroll
      for (int w0 = 12; w0 < 24; w0 += 4) {
        const float4 q = *reinterpret_cast<const float4*>(rp + w0);
        word(as_h2(q.x)); word(as_h2(q.y)); word(as_h2(q.z)); word(as_h2(q.w));
      }
      word(rp[24]);
      flush();

      pacc[lr * PACC + j] = fmaf(tm05, S2, 0.5f * S1);
    }
  }
  __syncthreads();

  // ---- per-row reduce: wave w handles rows 5w..5w+4 ----
  const int w    = tid >> 6;
  const int lane = tid & 63;
#pragma unroll
  for (int k = 0; k < 5; ++k) {
    const int lr   = w * 5 + k;
    const int grow = r0 + lr;
    float x = (lane < Q_DIM) ? pacc[lr * PACC + lane] : 0.0f;
#pragma unroll
    for (int off = 32; off > 0; off >>= 1)
      x += __shfl_xor(x, off, 64);
    if (lane == 0 && grow < NROW)
      out[grow] = x * (1.0f / Q_DIM);
  }
}

// ---------------------------------------------------------------------------
extern "C" void kernel_launch(void* const* d_in, const int* in_sizes, int n_in,
                              void* d_out, int out_size, void* d_ws, size_t ws_size,
                              hipStream_t stream) {
  const float* reward       = (const float*)d_in[0];
  const int*   step_type    = (const int*)  d_in[1];
  const float* discount     = (const float*)d_in[2];
  const float* value        = (const float*)d_in[3];
  const float* target_value = (const float*)d_in[4];
  float* out = (float*)d_out;

  float* alpha  = (float*)d_ws;              // [512][128]
  float* beta   = alpha + B_DIM * 128;
  int*   anchor = (int*)(beta + B_DIM * 128);

  coeff_kernel<<<B_DIM, 128, 0, stream>>>(reward, step_type, discount,
                                          alpha, beta, anchor, out);

  loss_kernel<<<GRID_LOSS, 256, 0, stream>>>(value, target_value,
                                             alpha, beta, anchor, out);
}